// Round 1
// baseline (224.768 us; speedup 1.0000x reference)
//
#include <hip/hip_runtime.h>
#include <math.h>

#define EPSF 1e-6f

typedef float v4f __attribute__((ext_vector_type(4)));
typedef int   v2i __attribute__((ext_vector_type(2)));

struct F3   { float x, y, z; };
struct Quat { float x, y, z, w; };
struct Sim3 { F3 t; Quat q; float s; };

__device__ __forceinline__ F3 cross3(F3 a, F3 b) {
    return { a.y*b.z - a.z*b.y, a.z*b.x - a.x*b.z, a.x*b.y - a.y*b.x };
}

__device__ __forceinline__ F3 quat_rotate(Quat q, F3 v) {
    F3 qv { q.x, q.y, q.z };
    F3 uv  = cross3(qv, v);
    F3 cuv = cross3(qv, uv);
    return { v.x + 2.0f*(q.w*uv.x + cuv.x),
             v.y + 2.0f*(q.w*uv.y + cuv.y),
             v.z + 2.0f*(q.w*uv.z + cuv.z) };
}

__device__ __forceinline__ Quat quat_mul(Quat a, Quat b) {
    return {
        a.w*b.x + a.x*b.w + a.y*b.z - a.z*b.y,
        a.w*b.y - a.x*b.z + a.y*b.w + a.z*b.x,
        a.w*b.z + a.x*b.y - a.y*b.x + a.z*b.w,
        a.w*b.w - a.x*b.x - a.y*b.y - a.z*b.z
    };
}

__device__ __forceinline__ Sim3 sim3_inv(Sim3 T) {
    Quat qi { -T.q.x, -T.q.y, -T.q.z, T.q.w };
    float si = __fdividef(1.0f, T.s);
    F3 r = quat_rotate(qi, T.t);
    return { { -si*r.x, -si*r.y, -si*r.z }, qi, si };
}

__device__ __forceinline__ Sim3 sim3_mul(Sim3 A, Sim3 B) {
    F3 r = quat_rotate(A.q, B.t);
    return { { A.t.x + A.s*r.x, A.t.y + A.s*r.y, A.t.z + A.s*r.z },
             quat_mul(A.q, B.q), A.s * B.s };
}

// rows are 8 floats = 32 B, base 256-B aligned -> v4f-safe
__device__ __forceinline__ Sim3 load_sim3(const float* __restrict__ p) {
    v4f a = *reinterpret_cast<const v4f*>(p);
    v4f b = *reinterpret_cast<const v4f*>(p + 4);
    return { {a.x, a.y, a.z}, {a.w, b.x, b.y, b.z}, b.w };
}

// nontemporal variant for one-shot streams (keeps L3 free for Twc gathers)
__device__ __forceinline__ Sim3 load_sim3_nt(const float* __restrict__ p) {
    v4f a = __builtin_nontemporal_load(reinterpret_cast<const v4f*>(p));
    v4f b = __builtin_nontemporal_load(reinterpret_cast<const v4f*>(p) + 1);
    return { {a.x, a.y, a.z}, {a.w, b.x, b.y, b.z}, b.w };
}

// atan2 for y >= 0 -> [0, pi].  A&S 4.4.49 polynomial, |err| <= 1e-5 rad.
// Output tolerance is 4.88 absmax -> 5 orders of magnitude of headroom.
__device__ __forceinline__ float fast_atan2_pos(float y, float x) {
    float ax = fabsf(x);
    float mn = fminf(y, ax);
    float mx = fmaxf(y, ax);
    float t  = __fdividef(mn, mx);     // [0,1]; mx>0 for unit quaternions
    float s  = t * t;
    float p  = fmaf(s, 0.0208351f, -0.0851330f);
    p = fmaf(s, p,  0.1801410f);
    p = fmaf(s, p, -0.3302995f);
    p = fmaf(s, p,  0.9998660f);
    float r = t * p;
    r = (y > ax)   ? (1.5707963268f - r) : r;
    r = (x < 0.0f) ? (3.1415926536f - r) : r;
    return r;
}

// out[0..2]=tau, out[3..5]=phi, out[6]=sigma — mirrors the jax reference
// branch-for-branch.  Transcendentals use native HW ops (__expf/__logf/
// __sinf/__cosf/__fdividef + poly atan2); Cramer solve stays in double
// (verified against the reference's f32 LU in the prior session).
__device__ __forceinline__ void sim3_log(Sim3 T, float out[7]) {
    float qx = T.q.x, qy = T.q.y, qz = T.q.z, qw = T.q.w;
    float nv = sqrtf(qx*qx + qy*qy + qz*qz);
    float theta_r = 2.0f * fast_atan2_pos(nv, qw);
    bool  nv_small = nv < EPSF;
    float fac = nv_small ? 2.0f : __fdividef(theta_r, nv);
    float px = fac*qx, py = fac*qy, pz = fac*qz;
    float sigma = __logf(T.s);
    // |phi| == fac*nv == theta_r (or 2*nv in the small branch) — skip the sqrt
    float theta = nv_small ? 2.0f*nv : theta_r;

    bool sig_small = fabsf(sigma) < EPSF;
    bool th_small  = theta < EPSF;
    float sg = sig_small ? 1.0f : sigma;
    float th = th_small  ? 1.0f : theta;
    float scale = __expf(sigma);
    float th2 = th*th, sg2 = sg*sg;
    float C = sig_small ? 1.0f : __fdividef(scale - 1.0f, sg);
    float sth = __sinf(th), cth = __cosf(th);
    float A_ss = th_small ? 0.5f : __fdividef(1.0f - cth, th2);
    float B_ss = th_small ? (1.0f/6.0f) : __fdividef(th - sth, th2 * th);
    float a = scale * sth;
    float b = scale * cth;
    float c = th2 + sg2;
    float rc = __fdividef(1.0f, c);
    float A_g = __fdividef(fmaf(a, sg, (1.0f - b)*th), th * c);
    float B_g = __fdividef(C - fmaf(b - 1.0f, sg, a*th) * rc, th2);
    float A_ts = __fdividef(fmaf(sg - 1.0f, scale, 1.0f), sg2);
    float B_ts = __fdividef(fmaf(scale, fmaf(sg, sg - 2.0f, 2.0f), -2.0f), 2.0f*sg2*sg);
    float A = sig_small ? A_ss : (th_small ? A_ts : A_g);
    float B = sig_small ? B_ss : (th_small ? B_ts : B_g);

    // Phi = skew(phi); Q = Phi @ Phi (explicit, matching reference order)
    float P01 = -pz, P02 =  py;
    float P10 =  pz, P12 = -px;
    float P20 = -py, P21 =  px;
    float Q00 = P01*P10 + P02*P20;
    float Q01 = P02*P21;
    float Q02 = P01*P12;
    float Q10 = P12*P20;
    float Q11 = P10*P01 + P12*P21;
    float Q12 = P10*P02;
    float Q20 = P21*P10;
    float Q21 = P20*P01;
    float Q22 = P20*P02 + P21*P12;

    float W00 = C + B*Q00,          W01 = A*P01 + B*Q01, W02 = A*P02 + B*Q02;
    float W10 = A*P10 + B*Q10,      W11 = C + B*Q11,     W12 = A*P12 + B*Q12;
    float W20 = A*P20 + B*Q20,      W21 = A*P21 + B*Q21, W22 = C + B*Q22;

    // tau = W^{-1} t  (Cramer/adjugate in double)
    double d00=W00, d01=W01, d02=W02, d10=W10, d11=W11, d12=W12, d20=W20, d21=W21, d22=W22;
    double c00 = d11*d22 - d12*d21;
    double c01 = d12*d20 - d10*d22;
    double c02 = d10*d21 - d11*d20;
    double det = d00*c00 + d01*c01 + d02*c02;
    double idet = 1.0 / det;
    double tx = T.t.x, ty = T.t.y, tz = T.t.z;
    out[0] = (float)((c00*tx + (d02*d21 - d01*d22)*ty + (d01*d12 - d02*d11)*tz) * idet);
    out[1] = (float)((c01*tx + (d00*d22 - d02*d20)*ty + (d02*d10 - d00*d12)*tz) * idet);
    out[2] = (float)((c02*tx + (d01*d20 - d00*d21)*ty + (d00*d11 - d01*d10)*tz) * idet);
    out[3] = px; out[4] = py; out[5] = pz; out[6] = sigma;
}

__global__ void __launch_bounds__(256) pgo_kernel(
        const float* __restrict__ Twc,
        const float* __restrict__ Tp_inv,
        const float* __restrict__ To_inv,
        const float* __restrict__ pw,
        const float* __restrict__ ow,
        const int*   __restrict__ edges,
        const float* __restrict__ T_lc,
        float*       __restrict__ out,
        int n) {
    int i = blockIdx.x * blockDim.x + threadIdx.x;
    if (i >= n) return;
    size_t i8 = (size_t)i * 8;
    size_t i7 = (size_t)i * 7;

    // ---- issue the long-latency random gathers FIRST so their ~300-900 cy
    // latency overlaps the prior/odom log chains ----
    v2i e = __builtin_nontemporal_load(
                reinterpret_cast<const v2i*>(edges + 2*(size_t)i));
    Sim3 Ta = load_sim3(Twc + (size_t)e.x * 8);   // keep cached (reused table)
    Sim3 Tb = load_sim3(Twc + (size_t)e.y * 8);
    Sim3 Tl = load_sim3_nt(T_lc + i8);            // one-shot stream -> NT

    // ---- streaming loads (issued early, consumed below) ----
    Sim3 Ti = load_sim3(Twc + i8);
    Sim3 Tj = load_sim3(Twc + i8 + 8);
    Sim3 Tp = load_sim3_nt(Tp_inv + i8);
    Sim3 To = load_sim3_nt(To_inv + i8);
    float pwv[7], owv[7];
    #pragma unroll
    for (int k = 0; k < 7; ++k) {
        pwv[k] = __builtin_nontemporal_load(pw + i7 + k);
        owv[k] = __builtin_nontemporal_load(ow + i7 + k);
    }

    Sim3 delta = sim3_mul(sim3_inv(Ti), Tj);

    float acc[7], r[7];
    sim3_log(sim3_mul(delta, Tp), r);
    #pragma unroll
    for (int k = 0; k < 7; ++k) acc[k] = r[k] * pwv[k];

    sim3_log(sim3_mul(delta, To), r);
    #pragma unroll
    for (int k = 0; k < 7; ++k) acc[k] = fmaf(r[k], owv[k], acc[k]);

    // gathers have had ~2 full log-chains of latency cover by now
    sim3_log(sim3_mul(sim3_mul(sim3_inv(Ta), Tb), Tl), r);
    #pragma unroll
    for (int k = 0; k < 7; ++k)
        __builtin_nontemporal_store(acc[k] + r[k], out + i7 + k);
}

extern "C" void kernel_launch(void* const* d_in, const int* in_sizes, int n_in,
                              void* d_out, int out_size, void* d_ws, size_t ws_size,
                              hipStream_t stream) {
    const float* Twc   = (const float*)d_in[0];
    const float* Tp    = (const float*)d_in[1];
    const float* To    = (const float*)d_in[2];
    const float* pw    = (const float*)d_in[3];
    const float* ow    = (const float*)d_in[4];
    const int*   edges = (const int*)d_in[5];
    const float* Tlc   = (const float*)d_in[6];
    float* out = (float*)d_out;

    int n = in_sizes[1] / 8;  // N_FRAME - 1
    const int block = 256;
    int grid = (n + block - 1) / block;
    pgo_kernel<<<grid, block, 0, stream>>>(Twc, Tp, To, pw, ow, edges, Tlc, out, n);
}

// Round 4
// 217.422 us; speedup vs baseline: 1.0338x; 1.0338x over previous
//
#include <hip/hip_runtime.h>
#include <math.h>

#define EPSF 1e-6f

typedef float v4f __attribute__((ext_vector_type(4)));
typedef int   v2i __attribute__((ext_vector_type(2)));

struct F3   { float x, y, z; };
struct Quat { float x, y, z, w; };
struct Sim3 { F3 t; Quat q; float s; };

__device__ __forceinline__ F3 cross3(F3 a, F3 b) {
    return { a.y*b.z - a.z*b.y, a.z*b.x - a.x*b.z, a.x*b.y - a.y*b.x };
}

__device__ __forceinline__ F3 quat_rotate(Quat q, F3 v) {
    F3 qv { q.x, q.y, q.z };
    F3 uv  = cross3(qv, v);
    F3 cuv = cross3(qv, uv);
    return { v.x + 2.0f*(q.w*uv.x + cuv.x),
             v.y + 2.0f*(q.w*uv.y + cuv.y),
             v.z + 2.0f*(q.w*uv.z + cuv.z) };
}

__device__ __forceinline__ Quat quat_mul(Quat a, Quat b) {
    return {
        a.w*b.x + a.x*b.w + a.y*b.z - a.z*b.y,
        a.w*b.y - a.x*b.z + a.y*b.w + a.z*b.x,
        a.w*b.z + a.x*b.y - a.y*b.x + a.z*b.w,
        a.w*b.w - a.x*b.x - a.y*b.y - a.z*b.z
    };
}

__device__ __forceinline__ Sim3 sim3_inv(Sim3 T) {
    Quat qi { -T.q.x, -T.q.y, -T.q.z, T.q.w };
    float si = __fdividef(1.0f, T.s);
    F3 r = quat_rotate(qi, T.t);
    return { { -si*r.x, -si*r.y, -si*r.z }, qi, si };
}

__device__ __forceinline__ Sim3 sim3_mul(Sim3 A, Sim3 B) {
    F3 r = quat_rotate(A.q, B.t);
    return { { A.t.x + A.s*r.x, A.t.y + A.s*r.y, A.t.z + A.s*r.z },
             quat_mul(A.q, B.q), A.s * B.s };
}

// rows are 8 floats = 32 B, base 256-B aligned -> v4f-safe
__device__ __forceinline__ Sim3 load_sim3(const float* __restrict__ p) {
    v4f a = *reinterpret_cast<const v4f*>(p);
    v4f b = *reinterpret_cast<const v4f*>(p + 4);
    return { {a.x, a.y, a.z}, {a.w, b.x, b.y, b.z}, b.w };
}

// nontemporal variant for one-shot streams (keeps L3 free for Twc gathers).
// NT *loads* proved out in round 1 (FETCH ~= compulsory). NT stores did NOT
// (1.7x write amplification) -- final store is now a plain cached store.
__device__ __forceinline__ Sim3 load_sim3_nt(const float* __restrict__ p) {
    v4f a = __builtin_nontemporal_load(reinterpret_cast<const v4f*>(p));
    v4f b = __builtin_nontemporal_load(reinterpret_cast<const v4f*>(p) + 1);
    return { {a.x, a.y, a.z}, {a.w, b.x, b.y, b.z}, b.w };
}

// atan2 for y >= 0 -> [0, pi].  A&S 4.4.49 polynomial, |err| <= 1e-5 rad.
// Output tolerance is 4.88 absmax -> 5 orders of magnitude of headroom.
__device__ __forceinline__ float fast_atan2_pos(float y, float x) {
    float ax = fabsf(x);
    float mn = fminf(y, ax);
    float mx = fmaxf(y, ax);
    float t  = __fdividef(mn, mx);     // [0,1]; mx>0 for unit quaternions
    float s  = t * t;
    float p  = fmaf(s, 0.0208351f, -0.0851330f);
    p = fmaf(s, p,  0.1801410f);
    p = fmaf(s, p, -0.3302995f);
    p = fmaf(s, p,  0.9998660f);
    float r = t * p;
    r = (y > ax)   ? (1.5707963268f - r) : r;
    r = (x < 0.0f) ? (3.1415926536f - r) : r;
    return r;
}

// out[0..2]=tau, out[3..5]=phi, out[6]=sigma — mirrors the jax reference
// branch-for-branch.  The generic (sig/theta not small) A,B,C path is
// computed under a wave-uniform branch (fallbacks are ~never taken for
// this data: sigma=0.1*N(0,1), theta from random unit quats).
// Cramer solve in f32 + one iterative-refinement step (replaces round-0's
// f64 Cramer: ~400 VALU-equivalents/thread cheaper, same accuracy class).
__device__ __forceinline__ void sim3_log(Sim3 T, float out[7]) {
    float qx = T.q.x, qy = T.q.y, qz = T.q.z, qw = T.q.w;
    float nv = sqrtf(qx*qx + qy*qy + qz*qz);
    float theta_r = 2.0f * fast_atan2_pos(nv, qw);
    bool  nv_small = nv < EPSF;
    float fac = nv_small ? 2.0f : __fdividef(theta_r, nv);
    float px = fac*qx, py = fac*qy, pz = fac*qz;
    float sigma = __logf(T.s);
    // |phi| == fac*nv == theta_r (or 2*nv in the small branch) — skip the sqrt
    float theta = nv_small ? 2.0f*nv : theta_r;

    bool sig_small = fabsf(sigma) < EPSF;
    bool th_small  = theta < EPSF;
    float scale = __expf(sigma);
    float A, B, C;
    if (!sig_small && !th_small) {
        // generic path only (wave-uniform for this data)
        float th = theta, sg = sigma;
        float th2 = th*th, sg2 = sg*sg;
        C = __fdividef(scale - 1.0f, sg);
        float sth = __sinf(th), cth = __cosf(th);
        float a = scale * sth;
        float b = scale * cth;
        float c = th2 + sg2;
        float rc = __fdividef(1.0f, c);
        A = __fdividef(fmaf(a, sg, (1.0f - b)*th), th * c);
        B = __fdividef(C - fmaf(b - 1.0f, sg, a*th) * rc, th2);
    } else {
        // full reference where() structure (rare)
        float sg = sig_small ? 1.0f : sigma;
        float th = th_small  ? 1.0f : theta;
        float th2 = th*th, sg2 = sg*sg;
        C = sig_small ? 1.0f : __fdividef(scale - 1.0f, sg);
        float sth = __sinf(th), cth = __cosf(th);
        float A_ss = th_small ? 0.5f : __fdividef(1.0f - cth, th2);
        float B_ss = th_small ? (1.0f/6.0f) : __fdividef(th - sth, th2 * th);
        float a = scale * sth;
        float b = scale * cth;
        float c = th2 + sg2;
        float rc = __fdividef(1.0f, c);
        float A_g = __fdividef(fmaf(a, sg, (1.0f - b)*th), th * c);
        float B_g = __fdividef(C - fmaf(b - 1.0f, sg, a*th) * rc, th2);
        float A_ts = __fdividef(fmaf(sg - 1.0f, scale, 1.0f), sg2);
        float B_ts = __fdividef(fmaf(scale, fmaf(sg, sg - 2.0f, 2.0f), -2.0f), 2.0f*sg2*sg);
        A = sig_small ? A_ss : (th_small ? A_ts : A_g);
        B = sig_small ? B_ss : (th_small ? B_ts : B_g);
    }

    // Phi = skew(phi); Q = Phi @ Phi (explicit, matching reference order)
    float P01 = -pz, P02 =  py;
    float P10 =  pz, P12 = -px;
    float P20 = -py, P21 =  px;
    float Q00 = P01*P10 + P02*P20;
    float Q01 = P02*P21;
    float Q02 = P01*P12;
    float Q10 = P12*P20;
    float Q11 = P10*P01 + P12*P21;
    float Q12 = P10*P02;
    float Q20 = P21*P10;
    float Q21 = P20*P01;
    float Q22 = P20*P02 + P21*P12;

    float W00 = C + B*Q00,          W01 = A*P01 + B*Q01, W02 = A*P02 + B*Q02;
    float W10 = A*P10 + B*Q10,      W11 = C + B*Q11,     W12 = A*P12 + B*Q12;
    float W20 = A*P20 + B*Q20,      W21 = A*P21 + B*Q21, W22 = C + B*Q22;

    // tau = W^{-1} t : f32 adjugate/Cramer + one refinement step
    float c00 = fmaf(W11, W22, -W12*W21);
    float c01 = fmaf(W12, W20, -W10*W22);
    float c02 = fmaf(W10, W21, -W11*W20);
    float a01 = fmaf(W02, W21, -W01*W22);
    float a02 = fmaf(W01, W12, -W02*W11);
    float a11 = fmaf(W00, W22, -W02*W20);
    float a12 = fmaf(W02, W10, -W00*W12);
    float a21 = fmaf(W01, W20, -W00*W21);
    float a22 = fmaf(W00, W11, -W01*W10);
    float det = fmaf(W00, c00, fmaf(W01, c01, W02*c02));
    float idet = __fdividef(1.0f, det);
    float tx = T.t.x, ty = T.t.y, tz = T.t.z;
    float t0 = fmaf(c00, tx, fmaf(a01, ty, a02*tz)) * idet;
    float t1 = fmaf(c01, tx, fmaf(a11, ty, a12*tz)) * idet;
    float t2 = fmaf(c02, tx, fmaf(a21, ty, a22*tz)) * idet;
    // refinement: tau += Adj(W)/det * (t - W tau)
    float r0 = tx - fmaf(W00, t0, fmaf(W01, t1, W02*t2));
    float r1 = ty - fmaf(W10, t0, fmaf(W11, t1, W12*t2));
    float r2 = tz - fmaf(W20, t0, fmaf(W21, t1, W22*t2));
    t0 = fmaf(fmaf(c00, r0, fmaf(a01, r1, a02*r2)), idet, t0);
    t1 = fmaf(fmaf(c01, r0, fmaf(a11, r1, a12*r2)), idet, t1);
    t2 = fmaf(fmaf(c02, r0, fmaf(a21, r1, a22*r2)), idet, t2);

    out[0] = t0; out[1] = t1; out[2] = t2;
    out[3] = px; out[4] = py; out[5] = pz; out[6] = sigma;
}

__global__ void __launch_bounds__(256) pgo_kernel(
        const float* __restrict__ Twc,
        const float* __restrict__ Tp_inv,
        const float* __restrict__ To_inv,
        const float* __restrict__ pw,
        const float* __restrict__ ow,
        const int*   __restrict__ edges,
        const float* __restrict__ T_lc,
        float*       __restrict__ out,
        int n) {
    int i = blockIdx.x * blockDim.x + threadIdx.x;
    if (i >= n) return;
    size_t i8 = (size_t)i * 8;
    size_t i7 = (size_t)i * 7;

    // ---- issue the long-latency random gathers FIRST so their ~300-900 cy
    // latency overlaps the prior/odom log chains ----
    v2i e = __builtin_nontemporal_load(
                reinterpret_cast<const v2i*>(edges + 2*(size_t)i));
    Sim3 Ta = load_sim3(Twc + (size_t)e.x * 8);   // keep cached (reused table)
    Sim3 Tb = load_sim3(Twc + (size_t)e.y * 8);
    Sim3 Tl = load_sim3_nt(T_lc + i8);            // one-shot stream -> NT

    // ---- streaming loads (issued early, consumed below) ----
    Sim3 Ti = load_sim3(Twc + i8);
    Sim3 Tj = load_sim3(Twc + i8 + 8);
    Sim3 Tp = load_sim3_nt(Tp_inv + i8);
    Sim3 To = load_sim3_nt(To_inv + i8);
    float pwv[7], owv[7];
    #pragma unroll
    for (int k = 0; k < 7; ++k) {
        pwv[k] = __builtin_nontemporal_load(pw + i7 + k);
        owv[k] = __builtin_nontemporal_load(ow + i7 + k);
    }

    Sim3 delta = sim3_mul(sim3_inv(Ti), Tj);

    float acc[7], r[7];
    sim3_log(sim3_mul(delta, Tp), r);
    #pragma unroll
    for (int k = 0; k < 7; ++k) acc[k] = r[k] * pwv[k];

    sim3_log(sim3_mul(delta, To), r);
    #pragma unroll
    for (int k = 0; k < 7; ++k) acc[k] = fmaf(r[k], owv[k], acc[k]);

    // gathers have had ~2 full log-chains of latency cover by now
    sim3_log(sim3_mul(sim3_mul(sim3_inv(Ta), Tb), Tl), r);
    // plain cached stores: contiguous 28 B/thread -> full-line L2
    // write-combining (round-1 NT stores caused 48 MB vs 28 MB ideal)
    #pragma unroll
    for (int k = 0; k < 7; ++k)
        out[i7 + k] = acc[k] + r[k];
}

extern "C" void kernel_launch(void* const* d_in, const int* in_sizes, int n_in,
                              void* d_out, int out_size, void* d_ws, size_t ws_size,
                              hipStream_t stream) {
    const float* Twc   = (const float*)d_in[0];
    const float* Tp    = (const float*)d_in[1];
    const float* To    = (const float*)d_in[2];
    const float* pw    = (const float*)d_in[3];
    const float* ow    = (const float*)d_in[4];
    const int*   edges = (const int*)d_in[5];
    const float* Tlc   = (const float*)d_in[6];
    float* out = (float*)d_out;

    int n = in_sizes[1] / 8;  // N_FRAME - 1
    const int block = 256;
    int grid = (n + block - 1) / block;
    pgo_kernel<<<grid, block, 0, stream>>>(Twc, Tp, To, pw, ow, edges, Tlc, out, n);
}